// Round 1
// baseline (359.228 us; speedup 1.0000x reference)
//
#include <hip/hip_runtime.h>

#define Hd 128
#define Nn 512
#define TJ 64
#define LSTRIDE 136  // bf16 elements per LDS tile row (128 + 8 pad, keeps 16B align)

typedef __bf16 bf16x8 __attribute__((ext_vector_type(8)));
typedef float  floatx4 __attribute__((ext_vector_type(4)));

__device__ __forceinline__ float fsilu(float x){ return x / (1.f + __expf(-x)); }
__device__ __forceinline__ float fsigm(float x){ return 1.f / (1.f + __expf(-x)); }
__device__ __forceinline__ float ftanh(float x){ return 1.f - 2.f / (__expf(2.f*x) + 1.f); }

// ---------------------------------------------------------------------------
// prep_ab: A[row] = h[row] @ We1[0:128] + be1 ;  Bm[row] = h[row] @ We1[128:256]
// ---------------------------------------------------------------------------
__global__ __launch_bounds__(128) void prep_ab(const float* __restrict__ h,
                                               const float* __restrict__ We1,
                                               const float* __restrict__ be1,
                                               float* __restrict__ A,
                                               float* __restrict__ Bm){
  const int row = blockIdx.x;
  const int k = threadIdx.x;
  __shared__ float hL[Hd];
  hL[k] = h[row*Hd + k];
  __syncthreads();
  float a = be1[k], bm = 0.f;
  #pragma unroll 4
  for (int c = 0; c < Hd; ++c){
    const float hv = hL[c];
    a  += hv * We1[c*Hd + k];
    bm += hv * We1[(c + Hd)*Hd + k];
  }
  A[row*Hd + k] = a;
  Bm[row*Hd + k] = bm;
}

// ---------------------------------------------------------------------------
// prep_sw: swizzle We2 / Wp1 / Wv1 (fp32, [k][col] row-major) into bf16
// MFMA B-operand fragment order: [ntile][kstep][lane][8], element
//   B[k = 32*s + (lane>>4)*8 + j][col = 16*n + (lane&15)]
// ---------------------------------------------------------------------------
__global__ __launch_bounds__(256) void prep_sw(const float* __restrict__ We2,
                                               const float* __restrict__ Wp1,
                                               const float* __restrict__ Wv1,
                                               __bf16* __restrict__ dst){
  const float* src = (blockIdx.x == 0) ? We2 : (blockIdx.x == 1 ? Wp1 : Wv1);
  __bf16* d = dst + blockIdx.x * (Hd*Hd);
  for (int idx = threadIdx.x; idx < Hd*Hd; idx += 256){
    const int j    = idx & 7;
    const int lane = (idx >> 3) & 63;
    const int s    = (idx >> 9) & 3;
    const int n    = idx >> 11;
    const int kk = 32*s + (lane >> 4)*8 + j;
    const int cc = 16*n + (lane & 15);
    d[idx] = (__bf16)src[kk*Hd + cc];
  }
}

// ---------------------------------------------------------------------------
// K-loop: 64x32(per-wave-cols) GEMM slice, A from LDS tile, B from global
// (pre-swizzled).  Wave w covers cols [32w, 32w+32).  Msub=4, Nsub=2.
// ---------------------------------------------------------------------------
__device__ __forceinline__ void gemm_kloop(const __bf16* __restrict__ buf,
                                           const bf16x8* __restrict__ Bs,
                                           int w, int lane, int q, int l15,
                                           floatx4 acc[4][2]){
  const floatx4 zero = {0.f, 0.f, 0.f, 0.f};
  #pragma unroll
  for (int m = 0; m < 4; ++m){ acc[m][0] = zero; acc[m][1] = zero; }
  #pragma unroll
  for (int s = 0; s < 4; ++s){
    bf16x8 af[4];
    #pragma unroll
    for (int m = 0; m < 4; ++m)
      af[m] = *(const bf16x8*)&buf[(16*m + l15)*LSTRIDE + s*32 + q*8];
    const bf16x8 b0 = Bs[((2*w + 0)*4 + s)*64 + lane];
    const bf16x8 b1 = Bs[((2*w + 1)*4 + s)*64 + lane];
    #pragma unroll
    for (int m = 0; m < 4; ++m){
      acc[m][0] = __builtin_amdgcn_mfma_f32_16x16x32_bf16(af[m], b0, acc[m][0], 0, 0, 0);
      acc[m][1] = __builtin_amdgcn_mfma_f32_16x16x32_bf16(af[m], b1, acc[m][1], 0, 0, 0);
    }
  }
}

// epilogue for pos/vel heads: per-row dot( silu(acc+bias), wvec ), reduced
// over the wave's 32 cols via 16-lane butterfly, partial -> LDS part[w][row]
__device__ __forceinline__ void wdot_epilogue(floatx4 acc[4][2],
                                              const float* __restrict__ biasL,
                                              const float* __restrict__ wL,
                                              int w, int q, int l15,
                                              float (*part)[64]){
  float pr[16];
  #pragma unroll
  for (int k = 0; k < 16; ++k) pr[k] = 0.f;
  #pragma unroll
  for (int m = 0; m < 4; ++m){
    #pragma unroll
    for (int n2 = 0; n2 < 2; ++n2){
      const int c = 32*w + 16*n2 + l15;
      const float bb = biasL[c], ww = wL[c];
      #pragma unroll
      for (int r = 0; r < 4; ++r)
        pr[4*m + r] += fsilu(acc[m][n2][r] + bb) * ww;
    }
  }
  #pragma unroll
  for (int off = 1; off < 16; off <<= 1){
    #pragma unroll
    for (int k = 0; k < 16; ++k) pr[k] += __shfl_xor(pr[k], off, 64);
  }
  if (l15 == 0){
    #pragma unroll
    for (int m = 0; m < 4; ++m)
      *(float4*)&part[w][16*m + 4*q] = make_float4(pr[4*m+0], pr[4*m+1], pr[4*m+2], pr[4*m+3]);
  }
}

// ---------------------------------------------------------------------------
// main: per (b,i) block, loop j-tiles of 64, fused edge pipeline
// ---------------------------------------------------------------------------
__global__ __launch_bounds__(256, 2) void egnn_main(
    const float* __restrict__ pos, const float* __restrict__ vel,
    const float* __restrict__ We1, const float* __restrict__ be2,
    const float* __restrict__ Wa,  const float* __restrict__ ba,
    const float* __restrict__ bp1, const float* __restrict__ Wp2,
    const float* __restrict__ bv1, const float* __restrict__ Wv2,
    const float* __restrict__ A,   const float* __restrict__ Bm,
    const __bf16* __restrict__ Wsw,
    float* __restrict__ magg, float* __restrict__ posupd, float* __restrict__ velupd){

  const int t    = threadIdx.x;
  const int w    = t >> 6;
  const int lane = t & 63;
  const int q    = lane >> 4;
  const int l15  = lane & 15;
  const int bid  = blockIdx.x;
  const int b    = bid >> 9;
  const int i    = bid & (Nn - 1);

  __shared__ float posL[Nn*3], velL[Nn*3];
  __shared__ float AiL[Hd], wpL[Hd], wvL[Hd], be2L[Hd], bp1L[Hd], bv1L[Hd];
  __shared__ float WaL[Hd], Wp2L[Hd], Wv2L[Hd];
  __shared__ __align__(16) __bf16 bufm [TJ*LSTRIDE];
  __shared__ __align__(16) __bf16 bufij[TJ*LSTRIDE];
  __shared__ float attPart[4][64], posPart[4][64], velPart[4][64];

  for (int idx = t; idx < Nn*3; idx += 256){
    posL[idx] = pos[b*Nn*3 + idx];
    velL[idx] = vel[b*Nn*3 + idx];
  }
  if (t < Hd){
    AiL[t]  = A[bid*Hd + t];
    wpL[t]  = We1[256*Hd + t];
    wvL[t]  = We1[257*Hd + t];
    be2L[t] = be2[t]; bp1L[t] = bp1[t]; bv1L[t] = bv1[t];
    WaL[t]  = Wa[t];  Wp2L[t] = Wp2[t]; Wv2L[t] = Wv2[t];
  }
  const float baV = ba[0];
  __syncthreads();

  const float px = posL[i*3+0], py = posL[i*3+1], pz = posL[i*3+2];
  const float ux = velL[i*3+0], uy = velL[i*3+1], uz = velL[i*3+2];

  const bf16x8* We2s = (const bf16x8*)(Wsw);
  const bf16x8* Wp1s = (const bf16x8*)(Wsw + Hd*Hd);
  const bf16x8* Wv1s = (const bf16x8*)(Wsw + 2*Hd*Hd);

  float accP0=0.f, accP1=0.f, accP2=0.f, accV0=0.f, accV1=0.f, accV2=0.f;
  float maggAcc = 0.f;

  for (int jt = 0; jt < Nn/TJ; ++jt){
    const int j0 = jt * TJ;

    // -------- phase B: build m tile (edge MLP layer 1, fp32 -> bf16 LDS) ----
    {
      const int j = t >> 2, seg = t & 3;
      const int jg = j0 + j;
      const float dx = px - posL[jg*3+0], dy = py - posL[jg*3+1], dz = pz - posL[jg*3+2];
      const float dp = dx*dx + dy*dy + dz*dz;
      const float ex = ux - velL[jg*3+0], ey = uy - velL[jg*3+1], ez = uz - velL[jg*3+2];
      const float dv = ex*ex + ey*ey + ez*ez;
      const float* Bp = &Bm[((size_t)(b*Nn + jg))*Hd + seg*32];
      bf16x8* dst = (bf16x8*)&bufm[j*LSTRIDE + seg*32];
      #pragma unroll
      for (int u = 0; u < 4; ++u){
        bf16x8 o;
        #pragma unroll
        for (int e = 0; e < 8; ++e){
          const int hh = seg*32 + u*8 + e;
          const float v = AiL[hh] + Bp[u*8 + e] + dp*wpL[hh] + dv*wvL[hh];
          o[e] = (__bf16)fsilu(v);
        }
        dst[u] = o;
      }
    }
    __syncthreads();

    // -------- GEMM1: m @ We2 -> silu -> bufij (bf16) ; Wa-dot partials -----
    {
      floatx4 acc[4][2];
      gemm_kloop(bufm, We2s, w, lane, q, l15, acc);
      float aw[16];
      #pragma unroll
      for (int k = 0; k < 16; ++k) aw[k] = 0.f;
      #pragma unroll
      for (int m = 0; m < 4; ++m){
        #pragma unroll
        for (int n2 = 0; n2 < 2; ++n2){
          const int c = 32*w + 16*n2 + l15;
          const float bb = be2L[c], wa = WaL[c];
          #pragma unroll
          for (int r = 0; r < 4; ++r){
            const float sv = fsilu(acc[m][n2][r] + bb);
            bufij[(16*m + 4*q + r)*LSTRIDE + c] = (__bf16)sv;
            aw[4*m + r] += sv * wa;
          }
        }
      }
      #pragma unroll
      for (int off = 1; off < 16; off <<= 1){
        #pragma unroll
        for (int k = 0; k < 16; ++k) aw[k] += __shfl_xor(aw[k], off, 64);
      }
      if (l15 == 0){
        #pragma unroll
        for (int m = 0; m < 4; ++m)
          *(float4*)&attPart[w][16*m + 4*q] = make_float4(aw[4*m+0], aw[4*m+1], aw[4*m+2], aw[4*m+3]);
      }
    }
    __syncthreads();

    // -------- attention scale (in place on bufij) --------------------------
    {
      const int j = t >> 2, seg = t & 3;
      const float as = attPart[0][j] + attPart[1][j] + attPart[2][j] + attPart[3][j] + baV;
      const float att = fsigm(as);
      bf16x8* p = (bf16x8*)&bufij[j*LSTRIDE + seg*32];
      #pragma unroll
      for (int u = 0; u < 4; ++u){
        bf16x8 v = p[u];
        #pragma unroll
        for (int k = 0; k < 8; ++k) v[k] = (__bf16)((float)v[k] * att);
        p[u] = v;
      }
    }
    __syncthreads();

    // -------- GEMM2 (pos head) and GEMM3 (vel head) ------------------------
    {
      floatx4 acc[4][2];
      gemm_kloop(bufij, Wp1s, w, lane, q, l15, acc);
      wdot_epilogue(acc, bp1L, Wp2L, w, q, l15, posPart);
      gemm_kloop(bufij, Wv1s, w, lane, q, l15, acc);
      wdot_epilogue(acc, bv1L, Wv2L, w, q, l15, velPart);
    }
    __syncthreads();

    // -------- step 6: tanh weights + accumulation (register-resident) ------
    if (w == 0){
      const int jg = j0 + lane;
      const float s4 = posPart[0][lane] + posPart[1][lane] + posPart[2][lane] + posPart[3][lane];
      const float pw = ftanh(s4);
      accP0 += (px - posL[jg*3+0]) * pw;
      accP1 += (py - posL[jg*3+1]) * pw;
      accP2 += (pz - posL[jg*3+2]) * pw;
    } else if (w == 1){
      const int jg = j0 + lane;
      const float s4 = velPart[0][lane] + velPart[1][lane] + velPart[2][lane] + velPart[3][lane];
      const float vw = ftanh(s4);
      accV0 += (ux - velL[jg*3+0]) * vw;
      accV1 += (uy - velL[jg*3+1]) * vw;
      accV2 += (uz - velL[jg*3+2]) * vw;
    } else {
      const int hh = (w - 2)*64 + lane;
      float s = 0.f;
      #pragma unroll 8
      for (int j = 0; j < TJ; ++j) s += (float)bufij[j*LSTRIDE + hh];
      maggAcc += s;
    }
    // no tile-end barrier needed: next-tile consumers of bufij/parts are all
    // behind next-tile barriers that every wave (incl. 2/3) must reach.
  }

  // -------- block epilogue: reduce and write -------------------------------
  if (w == 0){
    float v0 = accP0, v1 = accP1, v2 = accP2;
    for (int off = 1; off < 64; off <<= 1){
      v0 += __shfl_xor(v0, off, 64);
      v1 += __shfl_xor(v1, off, 64);
      v2 += __shfl_xor(v2, off, 64);
    }
    if (lane == 0){
      posupd[bid*3+0] = v0; posupd[bid*3+1] = v1; posupd[bid*3+2] = v2;
    }
  } else if (w == 1){
    float v0 = accV0, v1 = accV1, v2 = accV2;
    for (int off = 1; off < 64; off <<= 1){
      v0 += __shfl_xor(v0, off, 64);
      v1 += __shfl_xor(v1, off, 64);
      v2 += __shfl_xor(v2, off, 64);
    }
    if (lane == 0){
      velupd[bid*3+0] = v0; velupd[bid*3+1] = v1; velupd[bid*3+2] = v2;
    }
  } else {
    magg[bid*Hd + (w - 2)*64 + lane] = maggAcc;
  }
}

// ---------------------------------------------------------------------------
// final: node MLP (fp32) + residual + pos/vel clamp
// ---------------------------------------------------------------------------
__global__ __launch_bounds__(128) void egnn_final(
    const float* __restrict__ h, const float* __restrict__ pos, const float* __restrict__ vel,
    const float* __restrict__ Wn1, const float* __restrict__ bn1,
    const float* __restrict__ Wn2, const float* __restrict__ bn2,
    const float* __restrict__ magg, const float* __restrict__ posupd,
    const float* __restrict__ velupd, float* __restrict__ out){
  const int bid = blockIdx.x;
  const int k = threadIdx.x;
  __shared__ float ni[2*Hd];
  __shared__ float t1[Hd];
  ni[k]      = h[bid*Hd + k];
  ni[Hd + k] = magg[bid*Hd + k];
  __syncthreads();
  float a = bn1[k];
  #pragma unroll 4
  for (int c = 0; c < 2*Hd; ++c) a += ni[c] * Wn1[c*Hd + k];
  t1[k] = fsilu(a);
  __syncthreads();
  float o = bn2[k];
  #pragma unroll 4
  for (int c = 0; c < Hd; ++c) o += t1[c] * Wn2[c*Hd + k];
  out[bid*Hd + k] = ni[k] + o;

  const float inv_denom = 1.f / 511.f;
  if (k < 3){
    float v = pos[bid*3 + k] + posupd[bid*3 + k] * inv_denom;
    out[Nn*2*Hd + bid*3 + k] = fminf(fmaxf(v, -100.f), 100.f);
  } else if (k < 6){
    const int d = k - 3;
    float v = vel[bid*3 + d] + velupd[bid*3 + d] * inv_denom;
    out[Nn*2*Hd + 2*Nn*3 + bid*3 + d] = fminf(fmaxf(v, -100.f), 100.f);
  }
}

// ---------------------------------------------------------------------------
extern "C" void kernel_launch(void* const* d_in, const int* in_sizes, int n_in,
                              void* d_out, int out_size, void* d_ws, size_t ws_size,
                              hipStream_t stream){
  const float* h   = (const float*)d_in[0];
  const float* pos = (const float*)d_in[1];
  const float* vel = (const float*)d_in[2];
  const float* We1 = (const float*)d_in[3];
  const float* be1 = (const float*)d_in[4];
  const float* We2 = (const float*)d_in[5];
  const float* be2 = (const float*)d_in[6];
  const float* Wa  = (const float*)d_in[7];
  const float* ba  = (const float*)d_in[8];
  const float* Wp1 = (const float*)d_in[9];
  const float* bp1 = (const float*)d_in[10];
  const float* Wp2 = (const float*)d_in[11];
  const float* Wv1 = (const float*)d_in[12];
  const float* bv1 = (const float*)d_in[13];
  const float* Wv2 = (const float*)d_in[14];
  const float* Wn1 = (const float*)d_in[15];
  const float* bn1 = (const float*)d_in[16];
  const float* Wn2 = (const float*)d_in[17];
  const float* bn2 = (const float*)d_in[18];

  float* ws = (float*)d_ws;
  float*  A    = ws;                    // 1024*128 floats
  float*  Bmm  = ws + 131072;           // 1024*128
  float*  magg = ws + 262144;           // 1024*128
  float*  posu = ws + 393216;           // 1024*3
  float*  velu = ws + 396288;           // 1024*3
  __bf16* Wsw  = (__bf16*)(ws + 399360); // 3*16384 bf16 (16B-aligned offset)

  prep_ab  <<<dim3(1024), dim3(128), 0, stream>>>(h, We1, be1, A, Bmm);
  prep_sw  <<<dim3(3),    dim3(256), 0, stream>>>(We2, Wp1, Wv1, Wsw);
  egnn_main<<<dim3(1024), dim3(256), 0, stream>>>(pos, vel, We1, be2, Wa, ba, bp1, Wp2,
                                                  bv1, Wv2, A, Bmm, Wsw, magg, posu, velu);
  egnn_final<<<dim3(1024), dim3(128), 0, stream>>>(h, pos, vel, Wn1, bn1, Wn2, bn2,
                                                   magg, posu, velu, (float*)d_out);
}

// Round 2
// 338.780 us; speedup vs baseline: 1.0604x; 1.0604x over previous
//
#include <hip/hip_runtime.h>

#define Hd 128
#define Nn 512
#define TJ 64
#define LSTRIDE 136  // bf16 elements per LDS tile row (128 + 8 pad, keeps 16B align)

typedef __bf16 bf16x8 __attribute__((ext_vector_type(8)));
typedef float  floatx4 __attribute__((ext_vector_type(4)));

__device__ __forceinline__ float frcp(float x){ return __builtin_amdgcn_rcpf(x); }
__device__ __forceinline__ float fsilu(float x){ return x * frcp(1.f + __expf(-x)); }
__device__ __forceinline__ float fsigm(float x){ return frcp(1.f + __expf(-x)); }
__device__ __forceinline__ float ftanh(float x){ return 1.f - 2.f * frcp(__expf(2.f*x) + 1.f); }

// ---------------------------------------------------------------------------
// prep (fused): blocks 0..255 -> A/Bm (4 rows each); 256..258 -> weight swizzle
// A[row] = h[row]@We1[0:128]+be1 ; Bm[row] = h[row]@We1[128:256]
// swizzle: B-fragment order [ntile][kstep][lane][8]:
//   B[k = 32*s + (lane>>4)*8 + j][col = 16*n + (lane&15)]
// ---------------------------------------------------------------------------
__global__ __launch_bounds__(128) void prep(const float* __restrict__ h,
                                            const float* __restrict__ We1,
                                            const float* __restrict__ be1,
                                            const float* __restrict__ We2,
                                            const float* __restrict__ Wp1,
                                            const float* __restrict__ Wv1,
                                            float* __restrict__ A,
                                            float* __restrict__ Bm,
                                            __bf16* __restrict__ dst){
  __shared__ float hL[4][Hd];
  const int k = threadIdx.x;
  if (blockIdx.x < 256){
    const int r0 = blockIdx.x * 4;
    #pragma unroll
    for (int rr = 0; rr < 4; ++rr) hL[rr][k] = h[(r0+rr)*Hd + k];
    __syncthreads();
    const float bb = be1[k];
    float a0=bb,a1=bb,a2=bb,a3=bb, m0=0,m1=0,m2=0,m3=0;
    #pragma unroll 4
    for (int c = 0; c < Hd; ++c){
      const float wa = We1[c*Hd + k];
      const float wb = We1[(c+Hd)*Hd + k];
      a0 += hL[0][c]*wa; a1 += hL[1][c]*wa; a2 += hL[2][c]*wa; a3 += hL[3][c]*wa;
      m0 += hL[0][c]*wb; m1 += hL[1][c]*wb; m2 += hL[2][c]*wb; m3 += hL[3][c]*wb;
    }
    A[(r0+0)*Hd+k]=a0; A[(r0+1)*Hd+k]=a1; A[(r0+2)*Hd+k]=a2; A[(r0+3)*Hd+k]=a3;
    Bm[(r0+0)*Hd+k]=m0; Bm[(r0+1)*Hd+k]=m1; Bm[(r0+2)*Hd+k]=m2; Bm[(r0+3)*Hd+k]=m3;
  } else {
    const int which = blockIdx.x - 256;
    const float* src = (which == 0) ? We2 : (which == 1 ? Wp1 : Wv1);
    __bf16* d = dst + which * (Hd*Hd);
    for (int idx = k; idx < Hd*Hd; idx += 128){
      const int j    = idx & 7;
      const int lane = (idx >> 3) & 63;
      const int s    = (idx >> 9) & 3;
      const int n    = idx >> 11;
      const int kk = 32*s + (lane >> 4)*8 + j;
      const int cc = 16*n + (lane & 15);
      d[idx] = (__bf16)src[kk*Hd + cc];
    }
  }
}

// ---------------------------------------------------------------------------
// K-loop: 64-row x 32-col (per wave) GEMM slice, A from LDS, B pre-swizzled.
// ---------------------------------------------------------------------------
__device__ __forceinline__ void gemm_kloop(const __bf16* __restrict__ buf,
                                           const bf16x8* __restrict__ Bs,
                                           int w, int lane, int q, int l15,
                                           floatx4 acc[4][2]){
  const floatx4 zero = {0.f, 0.f, 0.f, 0.f};
  #pragma unroll
  for (int m = 0; m < 4; ++m){ acc[m][0] = zero; acc[m][1] = zero; }
  #pragma unroll
  for (int s = 0; s < 4; ++s){
    bf16x8 af[4];
    #pragma unroll
    for (int m = 0; m < 4; ++m)
      af[m] = *(const bf16x8*)&buf[(16*m + l15)*LSTRIDE + s*32 + q*8];
    const bf16x8 b0 = Bs[((2*w + 0)*4 + s)*64 + lane];
    const bf16x8 b1 = Bs[((2*w + 1)*4 + s)*64 + lane];
    #pragma unroll
    for (int m = 0; m < 4; ++m){
      acc[m][0] = __builtin_amdgcn_mfma_f32_16x16x32_bf16(af[m], b0, acc[m][0], 0, 0, 0);
      acc[m][1] = __builtin_amdgcn_mfma_f32_16x16x32_bf16(af[m], b1, acc[m][1], 0, 0, 0);
    }
  }
}

// Folding transpose-reduce: pr[16] across the 16 lanes of a quarter-wave.
// Returns the full sum of local-row bitrev4(l15); 15 shuffles vs 64.
__device__ __forceinline__ float fold_reduce16(float pr[16], int lane){
  #pragma unroll
  for (int k = 0; k < 8; ++k){
    const float send = (lane & 1) ? pr[k] : pr[k+8];
    const float recv = __shfl_xor(send, 1, 64);
    pr[k] = ((lane & 1) ? pr[k+8] : pr[k]) + recv;
  }
  #pragma unroll
  for (int k = 0; k < 4; ++k){
    const float send = (lane & 2) ? pr[k] : pr[k+4];
    const float recv = __shfl_xor(send, 2, 64);
    pr[k] = ((lane & 2) ? pr[k+4] : pr[k]) + recv;
  }
  #pragma unroll
  for (int k = 0; k < 2; ++k){
    const float send = (lane & 4) ? pr[k] : pr[k+2];
    const float recv = __shfl_xor(send, 4, 64);
    pr[k] = ((lane & 4) ? pr[k+2] : pr[k]) + recv;
  }
  {
    const float send = (lane & 8) ? pr[0] : pr[1];
    const float recv = __shfl_xor(send, 8, 64);
    pr[0] = ((lane & 8) ? pr[1] : pr[0]) + recv;
  }
  return pr[0];
}
__device__ __forceinline__ int bitrev4(int x){
  return ((x&1)<<3) | ((x&2)<<1) | ((x&4)>>1) | ((x&8)>>3);
}

// silu+dot epilogue for pos/vel heads -> part[w][row]
__device__ __forceinline__ void wdot_epilogue(floatx4 acc[4][2],
                                              const float* __restrict__ biasL,
                                              const float* __restrict__ wL,
                                              int w, int lane, int q, int l15,
                                              float (*part)[64]){
  float pr[16];
  #pragma unroll
  for (int k = 0; k < 16; ++k) pr[k] = 0.f;
  #pragma unroll
  for (int m = 0; m < 4; ++m){
    #pragma unroll
    for (int n2 = 0; n2 < 2; ++n2){
      const int c = 32*w + 16*n2 + l15;
      const float bb = biasL[c], ww = wL[c];
      #pragma unroll
      for (int r = 0; r < 4; ++r)
        pr[4*m + r] += fsilu(acc[m][n2][r] + bb) * ww;
    }
  }
  const float v = fold_reduce16(pr, lane);
  const int row16 = bitrev4(l15);
  part[w][16*(row16 >> 2) + 4*q + (row16 & 3)] = v;
}

// ---------------------------------------------------------------------------
// main: per (b,i) block, loop j-tiles of 64, fused edge pipeline
// ---------------------------------------------------------------------------
__global__ __launch_bounds__(256, 3) void egnn_main(
    const float* __restrict__ pos, const float* __restrict__ vel,
    const float* __restrict__ We1, const float* __restrict__ be2,
    const float* __restrict__ Wa,  const float* __restrict__ ba,
    const float* __restrict__ bp1, const float* __restrict__ Wp2,
    const float* __restrict__ bv1, const float* __restrict__ Wv2,
    const float* __restrict__ A,   const float* __restrict__ Bm,
    const __bf16* __restrict__ Wsw,
    float* __restrict__ magg, float* __restrict__ posupd, float* __restrict__ velupd){

  const int t    = threadIdx.x;
  const int w    = t >> 6;
  const int lane = t & 63;
  const int q    = lane >> 4;
  const int l15  = lane & 15;
  const int bid  = blockIdx.x;
  const int b    = bid >> 9;
  const int i    = bid & (Nn - 1);

  __shared__ float AiL[Hd], wpL[Hd], wvL[Hd], be2L[Hd], bp1L[Hd], bv1L[Hd];
  __shared__ float WaL[Hd], Wp2L[Hd], Wv2L[Hd];
  __shared__ __align__(16) __bf16 bufm [TJ*LSTRIDE];
  __shared__ __align__(16) __bf16 bufij[TJ*LSTRIDE];
  __shared__ float attPart[4][64], posPart[4][64], velPart[4][64];

  if (t < Hd){
    AiL[t]  = A[bid*Hd + t];
    wpL[t]  = We1[256*Hd + t];
    wvL[t]  = We1[257*Hd + t];
    be2L[t] = be2[t]; bp1L[t] = bp1[t]; bv1L[t] = bv1[t];
    WaL[t]  = Wa[t];  Wp2L[t] = Wp2[t]; Wv2L[t] = Wv2[t];
  }
  const float baV = ba[0];
  const float* pi = &pos[(size_t)(b*Nn + i)*3];
  const float* vi = &vel[(size_t)(b*Nn + i)*3];
  const float px = pi[0], py = pi[1], pz = pi[2];
  const float ux = vi[0], uy = vi[1], uz = vi[2];
  __syncthreads();

  const bf16x8* We2s = (const bf16x8*)(Wsw);
  const bf16x8* Wp1s = (const bf16x8*)(Wsw + Hd*Hd);
  const bf16x8* Wv1s = (const bf16x8*)(Wsw + 2*Hd*Hd);

  float accP0=0.f, accP1=0.f, accP2=0.f, accV0=0.f, accV1=0.f, accV2=0.f;
  float acc8[8];
  #pragma unroll
  for (int e = 0; e < 8; ++e) acc8[e] = 0.f;

  for (int jt = 0; jt < Nn/TJ; ++jt){
    const int j0 = jt * TJ;

    // -------- phase B: edge MLP layer 1 (fp32 -> bf16 LDS tile) ------------
    {
      const int j = t >> 2, seg = t & 3;
      const int jg = j0 + j;
      const float* pj = &pos[(size_t)(b*Nn + jg)*3];
      const float* vj = &vel[(size_t)(b*Nn + jg)*3];
      const float dx = px - pj[0], dy = py - pj[1], dz = pz - pj[2];
      const float dp = dx*dx + dy*dy + dz*dz;
      const float ex = ux - vj[0], ey = uy - vj[1], ez = uz - vj[2];
      const float dv = ex*ex + ey*ey + ez*ez;
      const float* Bp = &Bm[((size_t)(b*Nn + jg))*Hd + seg*32];
      bf16x8* dstp = (bf16x8*)&bufm[j*LSTRIDE + seg*32];
      #pragma unroll
      for (int u = 0; u < 4; ++u){
        bf16x8 o;
        #pragma unroll
        for (int e = 0; e < 8; ++e){
          const int hh = seg*32 + u*8 + e;
          const float v = AiL[hh] + Bp[u*8 + e] + dp*wpL[hh] + dv*wvL[hh];
          o[e] = (__bf16)fsilu(v);
        }
        dstp[u] = o;
      }
    }
    __syncthreads();

    // -------- GEMM1: m @ We2 -> silu -> bufij ; Wa-dot partials ------------
    {
      floatx4 acc[4][2];
      gemm_kloop(bufm, We2s, w, lane, q, l15, acc);
      float aw[16];
      #pragma unroll
      for (int k = 0; k < 16; ++k) aw[k] = 0.f;
      #pragma unroll
      for (int m = 0; m < 4; ++m){
        #pragma unroll
        for (int n2 = 0; n2 < 2; ++n2){
          const int c = 32*w + 16*n2 + l15;
          const float bb = be2L[c], wa = WaL[c];
          #pragma unroll
          for (int r = 0; r < 4; ++r){
            const float sv = fsilu(acc[m][n2][r] + bb);
            bufij[(16*m + 4*q + r)*LSTRIDE + c] = (__bf16)sv;
            aw[4*m + r] += sv * wa;
          }
        }
      }
      const float v = fold_reduce16(aw, lane);
      const int row16 = bitrev4(l15);
      attPart[w][16*(row16 >> 2) + 4*q + (row16 & 3)] = v;
    }
    __syncthreads();

    // -------- attention scale (in place on bufij) --------------------------
    {
      const int j = t >> 2, seg = t & 3;
      const float as = attPart[0][j] + attPart[1][j] + attPart[2][j] + attPart[3][j] + baV;
      const float att = fsigm(as);
      bf16x8* p = (bf16x8*)&bufij[j*LSTRIDE + seg*32];
      #pragma unroll
      for (int u = 0; u < 4; ++u){
        bf16x8 v = p[u];
        #pragma unroll
        for (int k = 0; k < 8; ++k) v[k] = (__bf16)((float)v[k] * att);
        p[u] = v;
      }
    }
    __syncthreads();

    // -------- GEMM2 (pos head) and GEMM3 (vel head) ------------------------
    {
      floatx4 acc[4][2];
      gemm_kloop(bufij, Wp1s, w, lane, q, l15, acc);
      wdot_epilogue(acc, bp1L, Wp2L, w, lane, q, l15, posPart);
      gemm_kloop(bufij, Wv1s, w, lane, q, l15, acc);
      wdot_epilogue(acc, bv1L, Wv2L, w, lane, q, l15, velPart);
    }
    __syncthreads();

    // -------- step 6: tanh weights + accumulation (register-resident) ------
    if (w == 0){
      const int jg = j0 + lane;
      const float* pj = &pos[(size_t)(b*Nn + jg)*3];
      const float s4 = posPart[0][lane] + posPart[1][lane] + posPart[2][lane] + posPart[3][lane];
      const float pw = ftanh(s4);
      accP0 += (px - pj[0]) * pw;
      accP1 += (py - pj[1]) * pw;
      accP2 += (pz - pj[2]) * pw;
    } else if (w == 1){
      const int jg = j0 + lane;
      const float* vj = &vel[(size_t)(b*Nn + jg)*3];
      const float s4 = velPart[0][lane] + velPart[1][lane] + velPart[2][lane] + velPart[3][lane];
      const float vw = ftanh(s4);
      accV0 += (ux - vj[0]) * vw;
      accV1 += (uy - vj[1]) * vw;
      accV2 += (uz - vj[2]) * vw;
    } else {
      // m_agg partial scan: vectorized b128 column accumulation
      const int sg   = (w - 2)*8 + (lane & 7);
      const int jsub = lane >> 3;
      #pragma unroll
      for (int jj = 0; jj < 8; ++jj){
        const int j = jj*8 + jsub;
        const bf16x8 v = *(const bf16x8*)&bufij[j*LSTRIDE + sg*8];
        #pragma unroll
        for (int e = 0; e < 8; ++e) acc8[e] += (float)v[e];
      }
    }
    // next-tile writers of bufm/bufij/parts are all behind next-tile barriers
  }

  // -------- block epilogue: reduce and write -------------------------------
  if (w == 0){
    float v0 = accP0, v1 = accP1, v2 = accP2;
    #pragma unroll
    for (int off = 1; off < 64; off <<= 1){
      v0 += __shfl_xor(v0, off, 64);
      v1 += __shfl_xor(v1, off, 64);
      v2 += __shfl_xor(v2, off, 64);
    }
    if (lane == 0){
      posupd[bid*3+0] = v0; posupd[bid*3+1] = v1; posupd[bid*3+2] = v2;
    }
  } else if (w == 1){
    float v0 = accV0, v1 = accV1, v2 = accV2;
    #pragma unroll
    for (int off = 1; off < 64; off <<= 1){
      v0 += __shfl_xor(v0, off, 64);
      v1 += __shfl_xor(v1, off, 64);
      v2 += __shfl_xor(v2, off, 64);
    }
    if (lane == 0){
      velupd[bid*3+0] = v0; velupd[bid*3+1] = v1; velupd[bid*3+2] = v2;
    }
  } else {
    const int sg = (w - 2)*8 + (lane & 7);
    #pragma unroll
    for (int off = 8; off < 64; off <<= 1){
      #pragma unroll
      for (int e = 0; e < 8; ++e) acc8[e] += __shfl_xor(acc8[e], off, 64);
    }
    if ((lane >> 3) == 0){
      float4 lo = make_float4(acc8[0], acc8[1], acc8[2], acc8[3]);
      float4 hi = make_float4(acc8[4], acc8[5], acc8[6], acc8[7]);
      *(float4*)&magg[bid*Hd + sg*8 + 0] = lo;
      *(float4*)&magg[bid*Hd + sg*8 + 4] = hi;
    }
  }
}

// ---------------------------------------------------------------------------
// final: node MLP (fp32) + residual + pos/vel clamp; 8 rows per block
// ---------------------------------------------------------------------------
__global__ __launch_bounds__(128) void egnn_final(
    const float* __restrict__ h, const float* __restrict__ pos, const float* __restrict__ vel,
    const float* __restrict__ Wn1, const float* __restrict__ bn1,
    const float* __restrict__ Wn2, const float* __restrict__ bn2,
    const float* __restrict__ magg, const float* __restrict__ posupd,
    const float* __restrict__ velupd, float* __restrict__ out){
  const int r0 = blockIdx.x * 8;
  const int k = threadIdx.x;
  __shared__ float ni[8][2*Hd];
  __shared__ float t1[8][Hd];
  #pragma unroll
  for (int rr = 0; rr < 8; ++rr){
    ni[rr][k]      = h[(r0+rr)*Hd + k];
    ni[rr][Hd + k] = magg[(r0+rr)*Hd + k];
  }
  __syncthreads();
  {
    const float bb = bn1[k];
    float a[8];
    #pragma unroll
    for (int rr = 0; rr < 8; ++rr) a[rr] = bb;
    #pragma unroll 2
    for (int c = 0; c < 2*Hd; ++c){
      const float wv = Wn1[c*Hd + k];
      #pragma unroll
      for (int rr = 0; rr < 8; ++rr) a[rr] += ni[rr][c] * wv;
    }
    #pragma unroll
    for (int rr = 0; rr < 8; ++rr) t1[rr][k] = fsilu(a[rr]);
  }
  __syncthreads();
  {
    const float bb = bn2[k];
    float o[8];
    #pragma unroll
    for (int rr = 0; rr < 8; ++rr) o[rr] = bb;
    #pragma unroll 2
    for (int c = 0; c < Hd; ++c){
      const float wv = Wn2[c*Hd + k];
      #pragma unroll
      for (int rr = 0; rr < 8; ++rr) o[rr] += t1[rr][c] * wv;
    }
    #pragma unroll
    for (int rr = 0; rr < 8; ++rr) out[(r0+rr)*Hd + k] = ni[rr][k] + o[rr];
  }
  const float inv_denom = 1.f / 511.f;
  if (k < 24){
    const int rr = k / 3, d = k - rr*3;
    const int row = r0 + rr;
    float v = pos[row*3 + d] + posupd[row*3 + d] * inv_denom;
    out[Nn*2*Hd + row*3 + d] = fminf(fmaxf(v, -100.f), 100.f);
  } else if (k < 48){
    const int kk = k - 24;
    const int rr = kk / 3, d = kk - rr*3;
    const int row = r0 + rr;
    float v = vel[row*3 + d] + velupd[row*3 + d] * inv_denom;
    out[Nn*2*Hd + 2*Nn*3 + row*3 + d] = fminf(fmaxf(v, -100.f), 100.f);
  }
}

// ---------------------------------------------------------------------------
extern "C" void kernel_launch(void* const* d_in, const int* in_sizes, int n_in,
                              void* d_out, int out_size, void* d_ws, size_t ws_size,
                              hipStream_t stream){
  const float* h   = (const float*)d_in[0];
  const float* pos = (const float*)d_in[1];
  const float* vel = (const float*)d_in[2];
  const float* We1 = (const float*)d_in[3];
  const float* be1 = (const float*)d_in[4];
  const float* We2 = (const float*)d_in[5];
  const float* be2 = (const float*)d_in[6];
  const float* Wa  = (const float*)d_in[7];
  const float* ba  = (const float*)d_in[8];
  const float* Wp1 = (const float*)d_in[9];
  const float* bp1 = (const float*)d_in[10];
  const float* Wp2 = (const float*)d_in[11];
  const float* Wv1 = (const float*)d_in[12];
  const float* bv1 = (const float*)d_in[13];
  const float* Wv2 = (const float*)d_in[14];
  const float* Wn1 = (const float*)d_in[15];
  const float* bn1 = (const float*)d_in[16];
  const float* Wn2 = (const float*)d_in[17];
  const float* bn2 = (const float*)d_in[18];

  float* ws = (float*)d_ws;
  float*  A    = ws;                     // 1024*128 floats
  float*  Bmm  = ws + 131072;            // 1024*128
  float*  magg = ws + 262144;            // 1024*128
  float*  posu = ws + 393216;            // 1024*3
  float*  velu = ws + 396288;            // 1024*3
  __bf16* Wsw  = (__bf16*)(ws + 399360); // 3*16384 bf16 (16B-aligned offset)

  prep     <<<dim3(259),  dim3(128), 0, stream>>>(h, We1, be1, We2, Wp1, Wv1, A, Bmm, Wsw);
  egnn_main<<<dim3(1024), dim3(256), 0, stream>>>(pos, vel, We1, be2, Wa, ba, bp1, Wp2,
                                                  bv1, Wv2, A, Bmm, Wsw, magg, posu, velu);
  egnn_final<<<dim3(128), dim3(128), 0, stream>>>(h, pos, vel, Wn1, bn1, Wn2, bn2,
                                                  magg, posu, velu, (float*)d_out);
}

// Round 3
// 320.838 us; speedup vs baseline: 1.1197x; 1.0559x over previous
//
#include <hip/hip_runtime.h>

#define Hd 128
#define Nn 512
#define TJ 64
#define LSTRIDE 136  // bf16 per LDS tile row (128 + 8 pad; 272 B = 17*16 keeps b128 align)

typedef __bf16 bf16x8 __attribute__((ext_vector_type(8)));
typedef float  floatx4 __attribute__((ext_vector_type(4)));

__device__ __forceinline__ float frcp(float x){ return __builtin_amdgcn_rcpf(x); }
__device__ __forceinline__ float fsilu(float x){ return x * frcp(1.f + __expf(-x)); }
__device__ __forceinline__ float fsigm(float x){ return frcp(1.f + __expf(-x)); }
__device__ __forceinline__ float ftanh(float x){ return 1.f - 2.f * frcp(__expf(2.f*x) + 1.f); }
__device__ __forceinline__ float rfl(float x){
  return __int_as_float(__builtin_amdgcn_readfirstlane(__float_as_int(x)));
}

// ---------------------------------------------------------------------------
// prep (fused): blocks 0..255 -> A/Bm (4 rows each); 256..258 -> weight swizzle
// A[row] = h[row]@We1[0:128]+be1 ; Bm[row] = h[row]@We1[128:256]
// swizzle: B-fragment order [ntile][kstep][lane][8]:
//   B[k = 32*s + (lane>>4)*8 + j][col = 16*n + (lane&15)]
// ---------------------------------------------------------------------------
__global__ __launch_bounds__(128) void prep(const float* __restrict__ h,
                                            const float* __restrict__ We1,
                                            const float* __restrict__ be1,
                                            const float* __restrict__ We2,
                                            const float* __restrict__ Wp1,
                                            const float* __restrict__ Wv1,
                                            float* __restrict__ A,
                                            float* __restrict__ Bm,
                                            __bf16* __restrict__ dst){
  __shared__ float hL[4][Hd];
  const int k = threadIdx.x;
  if (blockIdx.x < 256){
    const int r0 = blockIdx.x * 4;
    #pragma unroll
    for (int rr = 0; rr < 4; ++rr) hL[rr][k] = h[(r0+rr)*Hd + k];
    __syncthreads();
    const float bb = be1[k];
    float a0=bb,a1=bb,a2=bb,a3=bb, m0=0,m1=0,m2=0,m3=0;
    #pragma unroll 4
    for (int c = 0; c < Hd; ++c){
      const float wa = We1[c*Hd + k];
      const float wb = We1[(c+Hd)*Hd + k];
      a0 += hL[0][c]*wa; a1 += hL[1][c]*wa; a2 += hL[2][c]*wa; a3 += hL[3][c]*wa;
      m0 += hL[0][c]*wb; m1 += hL[1][c]*wb; m2 += hL[2][c]*wb; m3 += hL[3][c]*wb;
    }
    A[(r0+0)*Hd+k]=a0; A[(r0+1)*Hd+k]=a1; A[(r0+2)*Hd+k]=a2; A[(r0+3)*Hd+k]=a3;
    Bm[(r0+0)*Hd+k]=m0; Bm[(r0+1)*Hd+k]=m1; Bm[(r0+2)*Hd+k]=m2; Bm[(r0+3)*Hd+k]=m3;
  } else {
    const int which = blockIdx.x - 256;
    const float* src = (which == 0) ? We2 : (which == 1 ? Wp1 : Wv1);
    __bf16* d = dst + which * (Hd*Hd);
    for (int idx = k; idx < Hd*Hd; idx += 128){
      const int j    = idx & 7;
      const int lane = (idx >> 3) & 63;
      const int s    = (idx >> 9) & 3;
      const int n    = idx >> 11;
      const int kk = 32*s + (lane >> 4)*8 + j;
      const int cc = 16*n + (lane & 15);
      d[idx] = (__bf16)src[kk*Hd + cc];
    }
  }
}

// ---------------------------------------------------------------------------
// K-loop: 64-row x 32-col (per wave) GEMM slice, A from LDS, B pre-swizzled.
// ---------------------------------------------------------------------------
__device__ __forceinline__ void gemm_kloop(const __bf16* __restrict__ buf,
                                           const bf16x8* __restrict__ Bs,
                                           int w, int lane, int q, int l15,
                                           floatx4 acc[4][2]){
  const floatx4 zero = {0.f, 0.f, 0.f, 0.f};
  #pragma unroll
  for (int m = 0; m < 4; ++m){ acc[m][0] = zero; acc[m][1] = zero; }
  #pragma unroll
  for (int s = 0; s < 4; ++s){
    bf16x8 af[4];
    #pragma unroll
    for (int m = 0; m < 4; ++m)
      af[m] = *(const bf16x8*)&buf[(16*m + l15)*LSTRIDE + s*32 + q*8];
    const bf16x8 b0 = Bs[((2*w + 0)*4 + s)*64 + lane];
    const bf16x8 b1 = Bs[((2*w + 1)*4 + s)*64 + lane];
    #pragma unroll
    for (int m = 0; m < 4; ++m){
      acc[m][0] = __builtin_amdgcn_mfma_f32_16x16x32_bf16(af[m], b0, acc[m][0], 0, 0, 0);
      acc[m][1] = __builtin_amdgcn_mfma_f32_16x16x32_bf16(af[m], b1, acc[m][1], 0, 0, 0);
    }
  }
}

// Folding transpose-reduce across the 16 lanes of a quarter-wave.
// Returns full sum of local-row bitrev4(l15); 15 shuffles.
__device__ __forceinline__ float fold_reduce16(float pr[16], int lane){
  #pragma unroll
  for (int k = 0; k < 8; ++k){
    const float send = (lane & 1) ? pr[k] : pr[k+8];
    const float recv = __shfl_xor(send, 1, 64);
    pr[k] = ((lane & 1) ? pr[k+8] : pr[k]) + recv;
  }
  #pragma unroll
  for (int k = 0; k < 4; ++k){
    const float send = (lane & 2) ? pr[k] : pr[k+4];
    const float recv = __shfl_xor(send, 2, 64);
    pr[k] = ((lane & 2) ? pr[k+4] : pr[k]) + recv;
  }
  #pragma unroll
  for (int k = 0; k < 2; ++k){
    const float send = (lane & 4) ? pr[k] : pr[k+2];
    const float recv = __shfl_xor(send, 4, 64);
    pr[k] = ((lane & 4) ? pr[k+2] : pr[k]) + recv;
  }
  {
    const float send = (lane & 8) ? pr[0] : pr[1];
    const float recv = __shfl_xor(send, 8, 64);
    pr[0] = ((lane & 8) ? pr[1] : pr[0]) + recv;
  }
  return pr[0];
}
__device__ __forceinline__ int bitrev4(int x){
  return ((x&1)<<3) | ((x&2)<<1) | ((x&4)>>1) | ((x&8)>>3);
}

// silu+dot epilogue for pos/vel heads -> part[w][row]; bias from LDS, w from global
__device__ __forceinline__ void wdot_epilogue(floatx4 acc[4][2],
                                              const float* __restrict__ biasL,
                                              const float* __restrict__ wG,
                                              int w, int lane, int q, int l15,
                                              float (*part)[64]){
  float pr[16];
  #pragma unroll
  for (int k = 0; k < 16; ++k) pr[k] = 0.f;
  const int c0 = 32*w + l15, c1 = c0 + 16;
  const float bb0 = biasL[c0], bb1 = biasL[c1];
  const float ww0 = wG[c0],    ww1 = wG[c1];
  #pragma unroll
  for (int m = 0; m < 4; ++m){
    #pragma unroll
    for (int r = 0; r < 4; ++r){
      pr[4*m + r] += fsilu(acc[m][0][r] + bb0) * ww0;
      pr[4*m + r] += fsilu(acc[m][1][r] + bb1) * ww1;
    }
  }
  const float v = fold_reduce16(pr, lane);
  const int row16 = bitrev4(l15);
  part[w][16*(row16 >> 2) + 4*q + (row16 & 3)] = v;
}

// ---------------------------------------------------------------------------
// main: per (b,i) block, loop j-tiles of 64, fused edge pipeline + node MLP
// ---------------------------------------------------------------------------
__global__ __launch_bounds__(256) void egnn_main(
    const float* __restrict__ h,
    const float* __restrict__ pos, const float* __restrict__ vel,
    const float* __restrict__ We1, const float* __restrict__ be2,
    const float* __restrict__ Wa,  const float* __restrict__ ba,
    const float* __restrict__ bp1, const float* __restrict__ Wp2,
    const float* __restrict__ bv1, const float* __restrict__ Wv2,
    const float* __restrict__ Wn1, const float* __restrict__ bn1,
    const float* __restrict__ Wn2, const float* __restrict__ bn2,
    const float* __restrict__ A,   const float* __restrict__ Bm,
    const __bf16* __restrict__ Wsw,
    float* __restrict__ out){

  const int t    = threadIdx.x;
  const int w    = t >> 6;
  const int lane = t & 63;
  const int q    = lane >> 4;
  const int l15  = lane & 15;
  const int bid  = blockIdx.x;
  const int b    = bid >> 9;
  const int i    = bid & (Nn - 1);

  // LDS: 34816 (tiles) + 2048 (parts) + 3072 (arrays) = 39936 B -> 4 blocks/CU
  __shared__ float AiL[Hd], wpL[Hd], wvL[Hd], be2L[Hd], bp1L[Hd], bv1L[Hd];
  __shared__ __align__(16) __bf16 bufm [TJ*LSTRIDE];
  __shared__ __align__(16) __bf16 bufij[TJ*LSTRIDE];
  __shared__ float partA[4][64];  // attention partials, then pos partials (phase-disjoint)
  __shared__ float partV[4][64];

  if (t < Hd){
    AiL[t]  = A[bid*Hd + t];
    wpL[t]  = We1[256*Hd + t];
    wvL[t]  = We1[257*Hd + t];
    be2L[t] = be2[t]; bp1L[t] = bp1[t]; bv1L[t] = bv1[t];
  }
  const float baV = ba[0];
  const float* pi = &pos[(size_t)(b*Nn + i)*3];
  const float* vi = &vel[(size_t)(b*Nn + i)*3];
  const float px = rfl(pi[0]), py = rfl(pi[1]), pz = rfl(pi[2]);
  const float ux = rfl(vi[0]), uy = rfl(vi[1]), uz = rfl(vi[2]);
  __syncthreads();

  const bf16x8* We2s = (const bf16x8*)(Wsw);
  const bf16x8* Wp1s = (const bf16x8*)(Wsw + Hd*Hd);
  const bf16x8* Wv1s = (const bf16x8*)(Wsw + 2*Hd*Hd);

  // unified per-wave accumulators: waves 0/1 use [0..2] (pos/vel), 2/3 use [0..7] (m_agg)
  float accR[8];
  #pragma unroll
  for (int e = 0; e < 8; ++e) accR[e] = 0.f;

  for (int jt = 0; jt < Nn/TJ; ++jt){
    const int j0 = jt * TJ;

    // -------- phase B: edge MLP layer 1 (fp32 -> bf16 LDS tile) ------------
    {
      const int j = t >> 2, seg = t & 3;
      const int jg = j0 + j;
      const float* pj = &pos[(size_t)(b*Nn + jg)*3];
      const float* vj = &vel[(size_t)(b*Nn + jg)*3];
      const float dx = px - pj[0], dy = py - pj[1], dz = pz - pj[2];
      const float dp = dx*dx + dy*dy + dz*dz;
      const float ex = ux - vj[0], ey = uy - vj[1], ez = uz - vj[2];
      const float dv = ex*ex + ey*ey + ez*ez;
      const float* Bp = &Bm[((size_t)(b*Nn + jg))*Hd + seg*32];
      bf16x8* dstp = (bf16x8*)&bufm[j*LSTRIDE + seg*32];
      #pragma unroll
      for (int u = 0; u < 4; ++u){
        bf16x8 o;
        #pragma unroll
        for (int e = 0; e < 8; ++e){
          const int hh = seg*32 + u*8 + e;
          const float v = AiL[hh] + Bp[u*8 + e] + dp*wpL[hh] + dv*wvL[hh];
          o[e] = (__bf16)fsilu(v);
        }
        dstp[u] = o;
      }
    }
    __syncthreads();

    // -------- GEMM1: m @ We2 -> silu -> bufij ; Wa-dot partials ------------
    {
      floatx4 acc[4][2];
      gemm_kloop(bufm, We2s, w, lane, q, l15, acc);
      float aw[16];
      #pragma unroll
      for (int k = 0; k < 16; ++k) aw[k] = 0.f;
      const int c0 = 32*w + l15, c1 = c0 + 16;
      const float bb0 = be2L[c0], bb1 = be2L[c1];
      const float wa0 = Wa[c0],   wa1 = Wa[c1];
      #pragma unroll
      for (int m = 0; m < 4; ++m){
        #pragma unroll
        for (int r = 0; r < 4; ++r){
          const int row = 16*m + 4*q + r;
          const float sv0 = fsilu(acc[m][0][r] + bb0);
          const float sv1 = fsilu(acc[m][1][r] + bb1);
          bufij[row*LSTRIDE + c0] = (__bf16)sv0;
          bufij[row*LSTRIDE + c1] = (__bf16)sv1;
          aw[4*m + r] += sv0*wa0 + sv1*wa1;
        }
      }
      const float v = fold_reduce16(aw, lane);
      const int row16 = bitrev4(l15);
      partA[w][16*(row16 >> 2) + 4*q + (row16 & 3)] = v;
    }
    __syncthreads();

    // -------- attention scale (in place on bufij) --------------------------
    {
      const int j = t >> 2, seg = t & 3;
      const float as = partA[0][j] + partA[1][j] + partA[2][j] + partA[3][j] + baV;
      const float att = fsigm(as);
      bf16x8* p = (bf16x8*)&bufij[j*LSTRIDE + seg*32];
      #pragma unroll
      for (int u = 0; u < 4; ++u){
        bf16x8 v = p[u];
        #pragma unroll
        for (int k = 0; k < 8; ++k) v[k] = (__bf16)((float)v[k] * att);
        p[u] = v;
      }
    }
    __syncthreads();

    // -------- GEMM2 (pos head, ->partA) and GEMM3 (vel head, ->partV) ------
    {
      floatx4 acc[4][2];
      gemm_kloop(bufij, Wp1s, w, lane, q, l15, acc);
      wdot_epilogue(acc, bp1L, Wp2, w, lane, q, l15, partA);
      gemm_kloop(bufij, Wv1s, w, lane, q, l15, acc);
      wdot_epilogue(acc, bv1L, Wv2, w, lane, q, l15, partV);
    }
    __syncthreads();

    // -------- step 6: tanh weights + accumulation (register-resident) ------
    if (w == 0){
      const int jg = j0 + lane;
      const float* pj = &pos[(size_t)(b*Nn + jg)*3];
      const float s4 = partA[0][lane] + partA[1][lane] + partA[2][lane] + partA[3][lane];
      const float pw = ftanh(s4);
      accR[0] += (px - pj[0]) * pw;
      accR[1] += (py - pj[1]) * pw;
      accR[2] += (pz - pj[2]) * pw;
    } else if (w == 1){
      const int jg = j0 + lane;
      const float* vj = &vel[(size_t)(b*Nn + jg)*3];
      const float s4 = partV[0][lane] + partV[1][lane] + partV[2][lane] + partV[3][lane];
      const float vw = ftanh(s4);
      accR[0] += (ux - vj[0]) * vw;
      accR[1] += (uy - vj[1]) * vw;
      accR[2] += (uz - vj[2]) * vw;
    } else {
      // m_agg partial scan: vectorized b128 column accumulation
      const int sg   = (w - 2)*8 + (lane & 7);
      const int jsub = lane >> 3;
      #pragma unroll
      for (int jj = 0; jj < 8; ++jj){
        const int j = jj*8 + jsub;
        const bf16x8 v = *(const bf16x8*)&bufij[j*LSTRIDE + sg*8];
        #pragma unroll
        for (int e = 0; e < 8; ++e) accR[e] += (float)v[e];
      }
    }
    // next-tile writers of bufm/bufij/parts are all behind next-tile barriers
  }

  // -------- fused epilogue: magg -> LDS, pos/vel out, node MLP -------------
  float* sF = (float*)bufm;   // reuse 16.9 KB tile as fp32 scratch
  // layout: [0..127]=magg, [128..255]=hL, [256..383]=t1, [384..639]=partials
  __syncthreads();            // all waves past last step-6 before clobbering LDS

  if (t < 128) sF[128 + t] = h[bid*Hd + t];

  if (w == 0){
    float v0 = accR[0], v1 = accR[1], v2 = accR[2];
    #pragma unroll
    for (int off = 1; off < 64; off <<= 1){
      v0 += __shfl_xor(v0, off, 64);
      v1 += __shfl_xor(v1, off, 64);
      v2 += __shfl_xor(v2, off, 64);
    }
    if (lane == 0){
      const float inv_denom = 1.f / 511.f;
      float o0 = pi[0] + v0*inv_denom, o1 = pi[1] + v1*inv_denom, o2 = pi[2] + v2*inv_denom;
      out[2*Nn*Hd + bid*3 + 0] = fminf(fmaxf(o0, -100.f), 100.f);
      out[2*Nn*Hd + bid*3 + 1] = fminf(fmaxf(o1, -100.f), 100.f);
      out[2*Nn*Hd + bid*3 + 2] = fminf(fmaxf(o2, -100.f), 100.f);
    }
  } else if (w == 1){
    float v0 = accR[0], v1 = accR[1], v2 = accR[2];
    #pragma unroll
    for (int off = 1; off < 64; off <<= 1){
      v0 += __shfl_xor(v0, off, 64);
      v1 += __shfl_xor(v1, off, 64);
      v2 += __shfl_xor(v2, off, 64);
    }
    if (lane == 0){
      const float inv_denom = 1.f / 511.f;
      float o0 = vi[0] + v0*inv_denom, o1 = vi[1] + v1*inv_denom, o2 = vi[2] + v2*inv_denom;
      out[2*Nn*Hd + 2*Nn*3 + bid*3 + 0] = fminf(fmaxf(o0, -100.f), 100.f);
      out[2*Nn*Hd + 2*Nn*3 + bid*3 + 1] = fminf(fmaxf(o1, -100.f), 100.f);
      out[2*Nn*Hd + 2*Nn*3 + bid*3 + 2] = fminf(fmaxf(o2, -100.f), 100.f);
    }
  } else {
    const int sg = (w - 2)*8 + (lane & 7);
    #pragma unroll
    for (int off = 8; off < 64; off <<= 1){
      #pragma unroll
      for (int e = 0; e < 8; ++e) accR[e] += __shfl_xor(accR[e], off, 64);
    }
    if ((lane >> 3) == 0){
      *(float4*)&sF[sg*8 + 0] = make_float4(accR[0], accR[1], accR[2], accR[3]);
      *(float4*)&sF[sg*8 + 4] = make_float4(accR[4], accR[5], accR[6], accR[7]);
    }
  }
  __syncthreads();

  // node MLP layer 1: 256 threads, k = t&127, input half = t>>7
  {
    const int k = t & 127, half = t >> 7;
    const float* ni = &sF[half ? 0 : 128];        // half0: h, half1: magg
    const float* Wcol = &Wn1[(half*Hd)*Hd + k];
    float a = 0.f;
    #pragma unroll 4
    for (int c = 0; c < Hd; ++c) a += ni[c] * Wcol[c*Hd];
    sF[384 + half*128 + k] = a;
  }
  __syncthreads();
  if (t < 128) sF[256 + t] = fsilu(sF[384 + t] + sF[512 + t] + bn1[t]);
  __syncthreads();
  // layer 2: k = t&127, c-range half
  {
    const int k = t & 127, half = t >> 7;
    float o = 0.f;
    #pragma unroll 4
    for (int c0 = 0; c0 < 64; ++c0){
      const int c = half*64 + c0;
      o += sF[256 + c] * Wn2[c*Hd + k];
    }
    sF[384 + half*128 + k] = o;
  }
  __syncthreads();
  if (t < 128)
    out[bid*Hd + t] = sF[128 + t] + sF[384 + t] + sF[512 + t] + bn2[t];
}

// ---------------------------------------------------------------------------
extern "C" void kernel_launch(void* const* d_in, const int* in_sizes, int n_in,
                              void* d_out, int out_size, void* d_ws, size_t ws_size,
                              hipStream_t stream){
  const float* h   = (const float*)d_in[0];
  const float* pos = (const float*)d_in[1];
  const float* vel = (const float*)d_in[2];
  const float* We1 = (const float*)d_in[3];
  const float* be1 = (const float*)d_in[4];
  const float* We2 = (const float*)d_in[5];
  const float* be2 = (const float*)d_in[6];
  const float* Wa  = (const float*)d_in[7];
  const float* ba  = (const float*)d_in[8];
  const float* Wp1 = (const float*)d_in[9];
  const float* bp1 = (const float*)d_in[10];
  const float* Wp2 = (const float*)d_in[11];
  const float* Wv1 = (const float*)d_in[12];
  const float* bv1 = (const float*)d_in[13];
  const float* Wv2 = (const float*)d_in[14];
  const float* Wn1 = (const float*)d_in[15];
  const float* bn1 = (const float*)d_in[16];
  const float* Wn2 = (const float*)d_in[17];
  const float* bn2 = (const float*)d_in[18];

  float* ws = (float*)d_ws;
  float*  A    = ws;                     // 1024*128 floats
  float*  Bmm  = ws + 131072;            // 1024*128
  __bf16* Wsw  = (__bf16*)(ws + 262144); // 3*16384 bf16

  prep     <<<dim3(259),  dim3(128), 0, stream>>>(h, We1, be1, We2, Wp1, Wv1, A, Bmm, Wsw);
  egnn_main<<<dim3(1024), dim3(256), 0, stream>>>(h, pos, vel, We1, be2, Wa, ba, bp1, Wp2,
                                                  bv1, Wv2, Wn1, bn1, Wn2, bn2,
                                                  A, Bmm, Wsw, (float*)d_out);
}